// Round 6
// baseline (13.546 us; speedup 1.0000x reference)
//
#include <hip/hip_runtime.h>
#include <hip/hip_bf16.h>

#define H_MODEL 1024
#define N_STATE 32
#define L_LEN   2048
#define BLK     512
#define QL      128            // l-slots per block
#define GSTEP   16             // outputs per l-slot (QL * GSTEP == L_LEN)
#define NPQ     (N_STATE / 4)  // 8 n's per thread-quarter
#define NPAIR   (GSTEP / 2)

typedef float v2f __attribute__((ext_vector_type(2)));

#define LOG2E   1.44269504088896341f
#define INV2PI  0.15915494309189535f

__device__ __forceinline__ float vsin_rev(float x) {  // sin(2*pi*x), x in [0,1)
    float r; asm("v_sin_f32 %0, %1" : "=v"(r) : "v"(x)); return r;
}
__device__ __forceinline__ float vcos_rev(float x) {  // cos(2*pi*x)
    float r; asm("v_cos_f32 %0, %1" : "=v"(r) : "v"(x)); return r;
}
__device__ __forceinline__ float hw_exp(float x) {    // e^x
    return __builtin_amdgcn_exp2f(x * LOG2E);
}
__device__ __forceinline__ void hw_sincos(float x, float* s, float* c) { // radians
    const float u = __builtin_amdgcn_fractf(x * INV2PI);
    *s = vsin_rev(u);
    *c = vcos_rev(u);
}

__global__ __launch_bounds__(BLK, 8) void s4d_kernel(
    const float* __restrict__ log_dt,       // (H)
    const float* __restrict__ log_A_real,   // (H,N)
    const float* __restrict__ A_imag,       // (H,N)
    const float* __restrict__ B_re,         // (H,N)
    const float* __restrict__ B_im,         // (H,N)
    const float* __restrict__ C_re,         // (H,N)
    const float* __restrict__ C_im,         // (H,N)
    float* __restrict__ out)                // (H,L)
{
    const int h = blockIdx.x;

    __shared__ float4 s_c1[N_STATE];             // {dre*log2e, dim/2pi, wre, wim}
    __shared__ float4 s_c2[N_STATE];             // {w2re, w2im, a, b}
    __shared__ float2 s_c3[N_STATE];             // {a2, b2}
    __shared__ float  s_part[4][QL][GSTEP + 1];  // odd pad: conflict-free

    // Redundant setup: lanes 0-31 of EVERY wave compute all 32 n's and write
    // identical values (benign race) -> no single-wave serial phase; all
    // waves reach the barrier together.
    if ((threadIdx.x & 63) < N_STATE) {
        const int n   = threadIdx.x & (N_STATE - 1);
        const int idx = h * N_STATE + n;
        const float dt   = hw_exp(log_dt[h]);
        const float a_re = -hw_exp(log_A_real[idx]);
        const float a_im = A_imag[idx];
        const float dre  = a_re * dt;
        const float dim  = a_im * dt;

        // A_bar = exp(dtA)
        const float er = hw_exp(dre);
        float sn, cs;
        hw_sincos(dim, &sn, &cs);
        const float abar_re = er * cs;
        const float abar_im = er * sn;

        // q = (A_bar - 1) / A
        const float num_re = abar_re - 1.0f;
        const float num_im = abar_im;
        const float inv_d  = __builtin_amdgcn_rcpf(
            __builtin_fmaf(a_re, a_re, a_im * a_im));
        const float q_re   = (num_re * a_re + num_im * a_im) * inv_d;
        const float q_im   = (num_im * a_re - num_re * a_im) * inv_d;

        // B_bar = q * B ; w = C * B_bar
        const float br = B_re[idx], bi = B_im[idx];
        const float bb_re = q_re * br - q_im * bi;
        const float bb_im = q_re * bi + q_im * br;
        const float cr = C_re[idx], ci = C_im[idx];
        const float wre = cr * bb_re - ci * bb_im;
        const float wim = cr * bb_im + ci * bb_re;

        // E = exp(dtA * QL); recurrence coeffs + precombined w2 = w*E
        const float erB = hw_exp(dre * (float)QL);
        float snB, csB;
        hw_sincos(dim * (float)QL, &snB, &csB);
        const float Er = erB * csB;
        const float Ei = erB * snB;
        const float a  = 2.0f * Er;
        const float b  = -__builtin_fmaf(Er, Er, Ei * Ei);
        const float a2 = __builtin_fmaf(a, a, b + b);
        const float b2 = -(b * b);
        const float w2re = wre * Er - wim * Ei;
        const float w2im = wre * Ei + wim * Er;

        s_c1[n] = make_float4(dre * LOG2E, dim * INV2PI, wre, wim);
        s_c2[n] = make_float4(w2re, w2im, a, b);
        s_c3[n] = make_float2(a2, b2);
    }
    __syncthreads();

    const int   q  = threadIdx.x >> 7;        // n-quarter 0..3
    const int   l  = threadIdx.x & (QL - 1);  // l-slot 0..127
    const int   nb = q * NPQ;
    const float t  = (float)l;

    v2f acc[NPAIR];
    #pragma unroll
    for (int j = 0; j < NPAIR; ++j) acc[j] = (v2f){0.0f, 0.0f};

    #pragma unroll 2
    for (int jn = 0; jn < NPQ; ++jn) {
        const float4 c1 = s_c1[nb + jn];
        const float4 c2 = s_c2[nb + jn];
        const float2 c3 = s_c3[nb + jn];
        const v2f A2 = {c3.x, c3.x};
        const v2f B2 = {c3.y, c3.y};

        // e^{dre*l} and sincos(dim*l) via hw trans
        const float er = __builtin_amdgcn_exp2f(c1.x * t);
        const float uf = __builtin_amdgcn_fractf(c1.y * t);
        const float sn = vsin_rev(uf);
        const float cs = vcos_rev(uf);

        // r0 = Re(w z), r1 = Re(w E z) directly (no z0i needed)
        const float r0 = er * __builtin_fmaf(c1.z, cs, -(c1.w * sn));
        const float r1 = er * __builtin_fmaf(c2.x, cs, -(c2.y * sn));
        const float r2 = __builtin_fmaf(c2.z, r1, c2.w * r0);
        const float r3 = __builtin_fmaf(c2.z, r2, c2.w * r1);

        v2f P0 = {r0, r1};
        v2f P1 = {r2, r3};
        acc[0] += P0;
        acc[1] += P1;
        #pragma unroll
        for (int k = 2; k < NPAIR; ++k) {
            const v2f Pn = __builtin_elementwise_fma(A2, P1, B2 * P0);
            acc[k] += Pn;
            P0 = P1; P1 = Pn;
        }
    }

    // all quarters deposit; each quarter sums + stores 4 of 16 outputs
    #pragma unroll
    for (int j = 0; j < NPAIR; ++j) {
        s_part[q][l][2 * j]     = acc[j].x;
        s_part[q][l][2 * j + 1] = acc[j].y;
    }
    __syncthreads();

    {
        const int k0 = q * (GSTEP / 4);
        float* orow = out + h * L_LEN + l;
        #pragma unroll
        for (int j = 0; j < GSTEP / 4; ++j) {
            const int k = k0 + j;
            const float s = (s_part[0][l][k] + s_part[1][l][k])
                          + (s_part[2][l][k] + s_part[3][l][k]);
            orow[k * QL] = s;
        }
    }
}

extern "C" void kernel_launch(void* const* d_in, const int* in_sizes, int n_in,
                              void* d_out, int out_size, void* d_ws, size_t ws_size,
                              hipStream_t stream) {
    const float* log_dt     = (const float*)d_in[0];
    const float* log_A_real = (const float*)d_in[1];
    const float* A_imag     = (const float*)d_in[2];
    const float* B_re       = (const float*)d_in[3];
    const float* B_im       = (const float*)d_in[4];
    const float* C_re       = (const float*)d_in[5];
    const float* C_im       = (const float*)d_in[6];
    float* out              = (float*)d_out;

    s4d_kernel<<<dim3(H_MODEL), dim3(BLK), 0, stream>>>(
        log_dt, log_A_real, A_imag, B_re, B_im, C_re, C_im, out);
}

// Round 7
// 13.090 us; speedup vs baseline: 1.0348x; 1.0348x over previous
//
#include <hip/hip_runtime.h>
#include <hip/hip_bf16.h>

#define H_MODEL 1024
#define N_STATE 32
#define L_LEN   2048
#define BLK     512
#define QL      128            // l-slots per block
#define GSTEP   16             // outputs per l-slot (QL * GSTEP == L_LEN)
#define NPQ     (N_STATE / 4)  // 8 n's per thread-quarter
#define NPAIR   (GSTEP / 2)

typedef float v2f __attribute__((ext_vector_type(2)));

__device__ __forceinline__ float vsin_rev(float x) {  // sin(2*pi*x)
    float r; asm("v_sin_f32 %0, %1" : "=v"(r) : "v"(x)); return r;
}
__device__ __forceinline__ float vcos_rev(float x) {  // cos(2*pi*x)
    float r; asm("v_cos_f32 %0, %1" : "=v"(r) : "v"(x)); return r;
}

__global__ __launch_bounds__(BLK, 8) void s4d_kernel(
    const float* __restrict__ log_dt,       // (H)
    const float* __restrict__ log_A_real,   // (H,N)
    const float* __restrict__ A_imag,       // (H,N)
    const float* __restrict__ B_re,         // (H,N)
    const float* __restrict__ B_im,         // (H,N)
    const float* __restrict__ C_re,         // (H,N)
    const float* __restrict__ C_im,         // (H,N)
    float* __restrict__ out)                // (H,L)
{
    const int h = blockIdx.x;

    __shared__ float4 s_c1[N_STATE];             // {dre*log2e, dim/2pi, wre, wim}
    __shared__ float4 s_c2[N_STATE];             // {Er, Ei, a=2Er, b=-|E|^2}
    __shared__ float  s_part[4][QL][GSTEP + 1];  // odd pad: conflict-free

    if (threadIdx.x < N_STATE) {
        const int n   = threadIdx.x;
        const int idx = h * N_STATE + n;
        const float dt   = __expf(log_dt[h]);
        const float a_re = -__expf(log_A_real[idx]);
        const float a_im = A_imag[idx];
        const float dre  = a_re * dt;
        const float dim  = a_im * dt;

        // A_bar = exp(dtA)
        const float er = __expf(dre);
        float sn, cs;
        __sincosf(dim, &sn, &cs);
        const float abar_re = er * cs;
        const float abar_im = er * sn;

        // q = (A_bar - 1) / A
        const float num_re = abar_re - 1.0f;
        const float num_im = abar_im;
        const float inv_d  = 1.0f / (a_re * a_re + a_im * a_im);
        const float q_re   = (num_re * a_re + num_im * a_im) * inv_d;
        const float q_im   = (num_im * a_re - num_re * a_im) * inv_d;

        // B_bar = q * B ; w = C * B_bar
        const float br = B_re[idx], bi = B_im[idx];
        const float bb_re = q_re * br - q_im * bi;
        const float bb_im = q_re * bi + q_im * br;
        const float cr = C_re[idx], ci = C_im[idx];
        const float wre = cr * bb_re - ci * bb_im;
        const float wim = cr * bb_im + ci * bb_re;

        // E = exp(dtA * QL); pair-recurrence coeffs
        const float erB = __expf(dre * (float)QL);
        float snB, csB;
        __sincosf(dim * (float)QL, &snB, &csB);
        const float Er = erB * csB;
        const float Ei = erB * snB;
        // fold log2(e) and 1/(2pi) into the per-t transcendental args
        s_c1[n] = make_float4(dre * 1.44269504088896341f,
                              dim * 0.15915494309189535f, wre, wim);
        s_c2[n] = make_float4(Er, Ei, 2.0f * Er, -(Er * Er + Ei * Ei));
    }
    __syncthreads();

    const int   q  = threadIdx.x >> 7;        // n-quarter 0..3
    const int   l  = threadIdx.x & (QL - 1);  // l-slot 0..127
    const int   nb = q * NPQ;
    const float t  = (float)l;

    v2f acc[NPAIR];
    #pragma unroll
    for (int j = 0; j < NPAIR; ++j) acc[j] = (v2f){0.0f, 0.0f};

    #pragma unroll 2
    for (int jn = 0; jn < NPQ; ++jn) {
        const float4 c1 = s_c1[nb + jn];
        const float4 c2 = s_c2[nb + jn];

        // stride-2 coeffs: a2 = a^2 + 2b, b2 = -b^2
        const float a2 = __builtin_fmaf(c2.z, c2.z, c2.w + c2.w);
        const float b2 = -(c2.w * c2.w);
        const v2f A2 = {a2, a2};
        const v2f B2 = {b2, b2};

        // z0 = w * exp(dtA * l) via hw trans: exp2 + sin/cos in revolutions
        const float er = __builtin_amdgcn_exp2f(c1.x * t);
        const float uf = __builtin_amdgcn_fractf(c1.y * t);
        const float sn = vsin_rev(uf);
        const float cs = vcos_rev(uf);
        const float z0r = er * __builtin_fmaf(c1.z, cs, -(c1.w * sn));
        const float z0i = er * __builtin_fmaf(c1.w, cs,  (c1.z * sn));

        // heads r0..r3, then pair recurrence P_k = a2*P_{k-1} + b2*P_{k-2}
        const float r0 = z0r;
        const float r1 = __builtin_fmaf(z0r, c2.x, -(z0i * c2.y));
        const float r2 = __builtin_fmaf(c2.z, r1, c2.w * r0);
        const float r3 = __builtin_fmaf(c2.z, r2, c2.w * r1);

        v2f P0 = {r0, r1};
        v2f P1 = {r2, r3};
        acc[0] += P0;
        acc[1] += P1;
        #pragma unroll
        for (int k = 2; k < NPAIR; ++k) {
            const v2f Pn = __builtin_elementwise_fma(A2, P1, B2 * P0);
            acc[k] += Pn;
            P0 = P1; P1 = Pn;
        }
    }

    // all quarters deposit; each quarter sums + stores 4 of 16 outputs
    #pragma unroll
    for (int j = 0; j < NPAIR; ++j) {
        s_part[q][l][2 * j]     = acc[j].x;
        s_part[q][l][2 * j + 1] = acc[j].y;
    }
    __syncthreads();

    {
        const int k0 = q * (GSTEP / 4);
        float* orow = out + h * L_LEN + l;
        #pragma unroll
        for (int j = 0; j < GSTEP / 4; ++j) {
            const int k = k0 + j;
            const float s = (s_part[0][l][k] + s_part[1][l][k])
                          + (s_part[2][l][k] + s_part[3][l][k]);
            orow[k * QL] = s;
        }
    }
}

extern "C" void kernel_launch(void* const* d_in, const int* in_sizes, int n_in,
                              void* d_out, int out_size, void* d_ws, size_t ws_size,
                              hipStream_t stream) {
    const float* log_dt     = (const float*)d_in[0];
    const float* log_A_real = (const float*)d_in[1];
    const float* A_imag     = (const float*)d_in[2];
    const float* B_re       = (const float*)d_in[3];
    const float* B_im       = (const float*)d_in[4];
    const float* C_re       = (const float*)d_in[5];
    const float* C_im       = (const float*)d_in[6];
    float* out              = (float*)d_out;

    s4d_kernel<<<dim3(H_MODEL), dim3(BLK), 0, stream>>>(
        log_dt, log_A_real, A_imag, B_re, B_im, C_re, C_im, out);
}